// Round 6
// baseline (7681.863 us; speedup 1.0000x reference)
//
#include <hip/hip_runtime.h>

// LSTM forward: B=65536, T=20, I=36, H=30. Gate order i,f,g,o.
// Inputs (fp32): x[B,T,I], W_ih[4H,I], W_hh[4H,H], b_ih[4H], b_hh[4H]
// Output (fp32, concat): out[B,T,H], h_n[1,B,H], c_n[1,B,H]
//
// Ledger:
//  R4 gate-split: 525us, VGPR 56 (live ~100 -> was ALSO spilling, see below).
//  R5 (512,8): VGPR 32 + scratch, 2364us.
//  R6 x ping-pong regs: VGPR 64 + scratch, 715us.
//  R7 row-split (live ~105): VGPR 64 + spill, 2850us.
//  R8 R7+waves_per_eu(4,4): IGNORED - still VGPR 64 + spill, 2820us.
//  MODEL: backend pins this kernel at <=64 arch VGPRs; excess spills to
//  AGPRs (v_accvgpr_* = VALU ops -> R7/R8's inflated 87% VALUBusy) then
//  scratch. Attributes don't lift it. FIT THE KERNEL IN ~60 LIVE VGPRS.
//  R9 (this): R7 row-split, but x moves to LDS (x_lds[2][36][64], same
//  lane-minor conflict-free layout as h_lds), staged double-buffered with
//  load-early/ds_write-late so HBM latency hides under the FMA body.
//  Live = ax[32]+c[8]+stage[9]+temps ~ 58 <= 64 -> spill-proof.
//  LDS 33KB -> exactly 4 blocks/CU (grid is 1024 blocks = 4/CU).

constexpr int BB = 65536;
constexpr int TT = 20;
constexpr int II = 36;
constexpr int HH = 30;
constexpr int RPW = 8;   // rows per wave; waves own n0 in {0,8,15,22}
                         // rows 15,22 duplicated (bitwise-identical writes)

__device__ __forceinline__ float fast_sigmoid(float v) {
    float e = __expf(-v);                      // v_exp_f32
    return __builtin_amdgcn_rcpf(1.f + e);     // v_rcp_f32
}
__device__ __forceinline__ float fast_tanh(float v) {
    // 1 - 2/(exp(2v)+1): saturates to +/-1, no inf/inf NaN
    float e = __expf(2.f * v);
    return 1.f - 2.f * __builtin_amdgcn_rcpf(e + 1.f);
}

__global__ __launch_bounds__(256, 4) void lstm_fwd(
    const float* __restrict__ x,
    const float* __restrict__ Wih,   // [4H][II] row-major, gate rows i,f,g,o
    const float* __restrict__ Whh,   // [4H][HH]
    const float* __restrict__ bih,   // [4H]
    const float* __restrict__ bhh,   // [4H]
    float* __restrict__ out) {

    __shared__ float x_lds[2][II][64];   // 18 KB [buf][input k][elem]
    __shared__ float h_lds[2][HH][64];   // 15 KB [buf][hidden n][elem]

    const int lane = threadIdx.x & 63;
    const int w = __builtin_amdgcn_readfirstlane((int)(threadIdx.x >> 6)); // 0..3
    const int n0 = (w == 0) ? 0 : (w == 1) ? 8 : (w == 2) ? 15 : 22;
    const int k0 = 9 * w;               // x_lds rows this wave stages
    const int b = blockIdx.x * 64 + lane;

    const float* xrow = x + (size_t)b * TT * II;
    float* orow = out + (size_t)b * TT * HH;

    // wave-uniform weight/bias bases -> scalar (s_load) path
    const float* wiB = Wih + (size_t)n0 * II;   // row (g,r) at [(g*HH+r)*II]
    const float* whB = Whh + (size_t)n0 * HH;   // row (g,r) at [(g*HH+r)*HH]
    const float* biB = bih + n0;
    const float* bhB = bhh + n0;

    float c[RPW];
#pragma unroll
    for (int r = 0; r < RPW; r++) c[r] = 0.f;

    // zero h buffer 0 (the 4 waves' row sets cover all 30 rows)
#pragma unroll
    for (int r = 0; r < RPW; r++) h_lds[0][n0 + r][lane] = 0.f;

    // stage x[t=0]: wave w fills rows k0..k0+8; lane supplies its own b
    {
        float s[9];
#pragma unroll
        for (int kk = 0; kk < 9; kk++) s[kk] = xrow[k0 + kk];
#pragma unroll
        for (int kk = 0; kk < 9; kk++) x_lds[0][k0 + kk][lane] = s[kk];
    }
    __syncthreads();

    int p = 0;
#pragma unroll 1
    for (int t = 0; t < TT; t++) {
        // issue next-t x loads FIRST: ~9 transient regs, vmcnt wait lands
        // at the ds_write ~2000 VALU-cycles later (fully hidden)
        float s[9];
        if (t + 1 < TT) {
#pragma unroll
            for (int kk = 0; kk < 9; kk++) s[kk] = xrow[(t + 1) * II + k0 + kk];
        }

        // bias init (scalar pipe; compiler can hoist sums to SGPRs)
        float ax[RPW][4];
#pragma unroll
        for (int r = 0; r < RPW; r++)
#pragma unroll
            for (int g = 0; g < 4; g++)
                ax[r][g] = biB[g * HH + r] + bhB[g * HH + r];

        // x-dot: 36 conflict-free ds_read_b32, 32 indep FMA chains each
#pragma unroll
        for (int k = 0; k < II; k++) {
            float u = x_lds[p][k][lane];
#pragma unroll
            for (int r = 0; r < RPW; r++)
#pragma unroll
                for (int g = 0; g < 4; g++)
                    ax[r][g] += wiB[(g * HH + r) * II + k] * u;
        }

        // h-dot: 30 conflict-free ds_read_b32
#pragma unroll
        for (int k = 0; k < HH; k++) {
            float u = h_lds[p][k][lane];
#pragma unroll
            for (int r = 0; r < RPW; r++)
#pragma unroll
                for (int g = 0; g < 4; g++)
                    ax[r][g] += whB[(g * HH + r) * HH + k] * u;
        }

        // gates, state update, stores (owning wave only)
#pragma unroll
        for (int r = 0; r < RPW; r++) {
            float it = fast_sigmoid(ax[r][0]);
            float ft = fast_sigmoid(ax[r][1]);
            float gt = fast_tanh(ax[r][2]);
            float ot = fast_sigmoid(ax[r][3]);
            float cn = ft * c[r] + it * gt;
            c[r] = cn;
            float hn = ot * fast_tanh(cn);
            h_lds[p ^ 1][n0 + r][lane] = hn;   // dup rows: identical values
            orow[t * HH + n0 + r] = hn;
        }

        // write staged x for t+1 into the dead buffer (read finished at t-1)
        if (t + 1 < TT) {
#pragma unroll
            for (int kk = 0; kk < 9; kk++) x_lds[p ^ 1][k0 + kk][lane] = s[kk];
        }
        __syncthreads();
        p ^= 1;
    }

    // finals: h from last-written buffer, c from registers
    float* hN = out + (size_t)BB * TT * HH + (size_t)b * HH;
    float* cN = out + (size_t)BB * TT * HH + (size_t)BB * HH + (size_t)b * HH;
#pragma unroll
    for (int r = 0; r < RPW; r++) {
        hN[n0 + r] = h_lds[p][n0 + r][lane];
        cN[n0 + r] = c[r];
    }
}

extern "C" void kernel_launch(void* const* d_in, const int* in_sizes, int n_in,
                              void* d_out, int out_size, void* d_ws, size_t ws_size,
                              hipStream_t stream) {
    const float* x    = (const float*)d_in[0];
    const float* w_ih = (const float*)d_in[1];
    const float* w_hh = (const float*)d_in[2];
    const float* b_ih = (const float*)d_in[3];
    const float* b_hh = (const float*)d_in[4];
    float* out = (float*)d_out;

    hipLaunchKernelGGL(lstm_fwd, dim3(BB / 64), dim3(256), 0, stream,
                       x, w_ih, w_hh, b_ih, b_hh, out);
}